// Round 10
// baseline (1100.080 us; speedup 1.0000x reference)
//
#include <hip/hip_runtime.h>
#include <hip/hip_bf16.h>

typedef _Float16 f16;
typedef __attribute__((ext_vector_type(8))) _Float16 f16x8;
typedef __attribute__((ext_vector_type(4))) float f32x4;
typedef __attribute__((ext_vector_type(4))) unsigned int u32x4;
typedef __attribute__((ext_vector_type(2))) int i32x2;

#define TT 128

__device__ __forceinline__ float sigmoidf_(float x) { return 1.0f / (1.0f + __expf(-x)); }

// ---------------------------------------------------------------------------
// Fused prep: weight converts + xcat build (gate-GEMM A operand) + h0 seed +
// flag zeroing in ONE launch.
// xcat (232 x 2048 f16): rows 0..199 = [nt_emb | 0], rows 200..231 =
// [0 | rule_emb[init_prod]]. One GEMM against full W_ih then yields BOTH
// gate tables (zero halves contribute exact zeros).
__global__ __launch_bounds__(256) void k_prep(
    const float* __restrict__ W_ih, const float* __restrict__ W_hh,
    const float* __restrict__ Wz, const float* __restrict__ We,
    const float* __restrict__ Wc, const float* __restrict__ nt_emb,
    const float* __restrict__ rule_emb, const int* __restrict__ init_prod,
    const float* __restrict__ h0,
    f16* __restrict__ Wih_h, f16* __restrict__ Whh_h,
    f16* __restrict__ Wz_h, f16* __restrict__ We_h, f16* __restrict__ Wc_h,
    f16* __restrict__ xcat, f16* __restrict__ st, int* __restrict__ bar)
{
  const long nWih = 2097152, nWhh = 1048576, nWz = 524288, nWe = 524288,
             nWc = 786432;
  const long T0 = nWih, T1 = T0 + nWhh, T2 = T1 + nWz, T3 = T2 + nWe,
             T4 = T3 + nWc, T5 = T4 + 475136, T6 = T5 + 32768, T7 = T6 + 512;
  const long stride = (long)gridDim.x * 256;
  for (long i = (long)blockIdx.x * 256 + threadIdx.x; i < T7; i += stride) {
    if (i < T4) {              // float4 -> 4x f16 converts
      const float* src; f16* dst; long j;
      if (i < T0)      { src = W_ih; dst = Wih_h; j = i; }
      else if (i < T1) { src = W_hh; dst = Whh_h; j = i - T0; }
      else if (i < T2) { src = Wz;   dst = Wz_h;  j = i - T1; }
      else if (i < T3) { src = We;   dst = We_h;  j = i - T2; }
      else             { src = Wc;   dst = Wc_h;  j = i - T3; }
      float4 v = ((const float4*)src)[j];
      dst[j*4+0] = (f16)v.x; dst[j*4+1] = (f16)v.y;
      dst[j*4+2] = (f16)v.z; dst[j*4+3] = (f16)v.w;
    } else if (i < T5) {       // xcat build (232 x 2048)
      long j = i - T4; int row = (int)(j >> 11), col = (int)(j & 2047);
      float v = 0.f;
      if (row < 200) { if (col < 1024) v = nt_emb[(long)row * 1024 + col]; }
      else if (col >= 1024)
        v = rule_emb[(long)init_prod[row - 200] * 1024 + (col - 1024)];
      xcat[j] = (f16)v;
    } else if (i < T6) {       // h0 -> st slot 0 ([t][bx][b][jj] layout)
      long j = i - T5; int b = (int)(j >> 10), k = (int)(j & 1023);
      st[(long)(k >> 3) * 256 + b * 8 + (k & 7)] = (f16)h0[j];
    } else {                   // zero flags
      bar[i - T6] = 0;
    }
  }
}

// ---------------------------------------------------------------------------
// fp16 MFMA GEMM: C[M,N] = act( A[M,K] @ B[N,K]^T + bias1 + bias2 )
// 128x128 tile, BK=32, register-prefetch double buffer (R3-proven).
// bmod: B K-index wraps mod bmod. zdiv: split-K, partials at outF+slice*sSl.
// ilv: outF column remap col -> (col&1023)*4 + (col>>10)  (gate-interleave).
// brow0: biases applied only to rows >= brow0 (merged gate-table GEMM).
// tin/toutT/toutN: if set, the LAST gridDim.z layer's blocks transpose
//   tin (B,512,1024)fp32 -> toutT (B,H,L)f16 + toutN (B,L,H)f16 instead of
//   doing GEMM work -- hides the env transpose inside the zt GEMM launch
//   (the exact window where both ctx buffers are dead).
__global__ __launch_bounds__(256) void k_gemm(
    const f16* __restrict__ A, long lda, long sA,
    const f16* __restrict__ B, long ldb, long sB,
    float* __restrict__ outF, long ldF, long sF, long sSl,
    f16* __restrict__ outH, long ldH, long sH,
    f16* __restrict__ outH2, long ldH2, long sH2,
    f16* __restrict__ out2, long ld2, long s2,
    const float* __restrict__ bias1, const float* __restrict__ bias2,
    int M, int N, int K, int act, int bmod, int zdiv, int ilv,
    const float* __restrict__ tin, f16* __restrict__ toutT,
    f16* __restrict__ toutN, int brow0)
{
  __shared__ __align__(16) f16 As[128][40];
  __shared__ __align__(16) f16 Bs[128][40];
  const int tid = threadIdx.x;

  if (tin && blockIdx.z == gridDim.z - 1) {
    // ---------------- transpose side-crew ----------------
    __shared__ float ttile[32][33];
    const int me = blockIdx.y * gridDim.x + blockIdx.x;
    const int nblk = gridDim.x * gridDim.y;
    const int c = tid & 31, r = tid >> 5;
    for (int idx = me; idx < 16384; idx += nblk) {
      int b = idx >> 9, rr2 = idx & 511;
      int l0 = (rr2 & 15) * 32, h0v = (rr2 >> 4) * 32;
      const float* inb = tin + (long)b * 512 * 1024;
      f16* oTb = toutT + (long)b * 1024 * 512;
      f16* oNb = toutN + (long)b * 512 * 1024;
#pragma unroll
      for (int p = 0; p < 4; ++p) {
        float v = inb[(long)(l0 + r + p*8) * 1024 + h0v + c];
        ttile[r + p*8][c] = v;
        oNb[(long)(l0 + r + p*8) * 1024 + h0v + c] = (f16)v;
      }
      __syncthreads();
#pragma unroll
      for (int p = 0; p < 4; ++p)
        oTb[(long)(h0v + r + p*8) * 512 + l0 + c] = (f16)ttile[c][r + p*8];
      __syncthreads();
    }
    return;
  }

  const int w = tid >> 6, lane = tid & 63;
  const int wm = (w & 1) * 64, wn = (w >> 1) * 64;
  const int lr = lane >> 4, lc = lane & 15;
  const long m0 = (long)blockIdx.x * 128;
  const long n0 = (long)blockIdx.y * 128;
  int z = blockIdx.z, batch = z, slice = 0, Ks = K;
  if (zdiv > 1) { batch = z / zdiv; slice = z - batch * zdiv; Ks = K / zdiv; }
  const long kbeg = (long)slice * Ks;
  A += (long)batch * sA;
  B += (long)batch * sB;

  const int rr = tid >> 2, sg = (tid & 3) * 8;
  const int nIt = Ks / 32;

  uint4 pa[2], pb[2];
  {
    long k = kbeg;
    long kb = bmod ? (k & (bmod - 1)) : k;
#pragma unroll
    for (int p = 0; p < 2; ++p) {
      int row = p * 64 + rr;
      uint4 va = {0,0,0,0}, vb = {0,0,0,0};
      if (m0 + row < M) va = *(const uint4*)(A + (m0 + row) * lda + k + sg);
      if (n0 + row < N) vb = *(const uint4*)(B + (n0 + row) * ldb + kb + sg);
      pa[p] = va; pb[p] = vb;
    }
  }

  f32x4 acc[4][4];
#pragma unroll
  for (int i = 0; i < 4; ++i)
#pragma unroll
    for (int j = 0; j < 4; ++j) { f32x4 zz = {0.f,0.f,0.f,0.f}; acc[i][j] = zz; }

  for (int it = 0; it < nIt; ++it) {
#pragma unroll
    for (int p = 0; p < 2; ++p) {
      *(uint4*)&As[p * 64 + rr][sg] = pa[p];
      *(uint4*)&Bs[p * 64 + rr][sg] = pb[p];
    }
    __syncthreads();
    if (it + 1 < nIt) {
      long k = kbeg + (long)(it + 1) * 32;
      long kb = bmod ? (k & (bmod - 1)) : k;
#pragma unroll
      for (int p = 0; p < 2; ++p) {
        int row = p * 64 + rr;
        uint4 va = {0,0,0,0}, vb = {0,0,0,0};
        if (m0 + row < M) va = *(const uint4*)(A + (m0 + row) * lda + k + sg);
        if (n0 + row < N) vb = *(const uint4*)(B + (n0 + row) * ldb + kb + sg);
        pa[p] = va; pb[p] = vb;
      }
    }
    f16x8 af[4], bf[4];
#pragma unroll
    for (int i = 0; i < 4; ++i) af[i] = *(const f16x8*)&As[wm + i*16 + lc][lr * 8];
#pragma unroll
    for (int j = 0; j < 4; ++j) bf[j] = *(const f16x8*)&Bs[wn + j*16 + lc][lr * 8];
#pragma unroll
    for (int i = 0; i < 4; ++i)
#pragma unroll
      for (int j = 0; j < 4; ++j)
        acc[i][j] = __builtin_amdgcn_mfma_f32_16x16x32_f16(af[i], bf[j], acc[i][j], 0, 0, 0);
    __syncthreads();
  }

  if (outF)  outF  += (long)batch * sF + (long)slice * sSl;
  if (outH)  outH  += (long)batch * sH;
  if (outH2) outH2 += (long)batch * sH2;
  if (out2)  out2  += (long)batch * s2;
#pragma unroll
  for (int i = 0; i < 4; ++i)
#pragma unroll
    for (int j = 0; j < 4; ++j)
#pragma unroll
      for (int r = 0; r < 4; ++r) {
        long row = m0 + wm + i * 16 + lr * 4 + r;
        long col = n0 + wn + j * 16 + lc;
        if (row < M && col < N) {
          float v = acc[i][j][r];
          if (row >= brow0) {
            if (bias1) v += bias1[col];
            if (bias2) v += bias2[col];
          }
          if (act)   v = tanhf(v);
          if (outF) {
            long fc = ilv ? ((col & 1023) * 4 + (col >> 10)) : col;
            outF[row * ldF + fc] = v;
          }
          if (outH)  outH[row * ldH + col] = (f16)v;
          if (outH2) outH2[row * ldH2 + col] = (f16)v;
          if (out2) {
            f16 hi = (f16)v;
            out2[row * ld2 + col]        = hi;
            out2[row * ld2 + 1024 + col] = (f16)(v - (float)hi);
          }
        }
      }
}

// ---------------------------------------------------------------------------
// Persistent LSTM (R3-proven flag-gated dataflow) + hidden NL transpose.
// 256 blocks x 256 threads, 1 block/CU:
//   blocks 0..127:  the R3 LSTM (verified 495-504us across R3/R8/R9).
//   blocks 128..255: transpose nl -> ctxT/ctx_h on the otherwise-idle half,
//     hidden under the LSTM's latency-bound shadow (R8/R9 verified). env is
//     transposed later INSIDE the zt GEMM launch into the SAME two buffers.
__global__ __launch_bounds__(256) void k_lstm_all(
    const f16* __restrict__ Whh,          // (4096,1024)
    const float* __restrict__ nt_table,   // (232,1024,4) gate-interleaved
    const float* __restrict__ prod_gates, // rows 200+ of nt_table
    const int* __restrict__ nt_ids,       // (128,32)
    const float* __restrict__ c0,         // (32,1024)
    f16* __restrict__ st,                 // (129,128,32,8) step/block-major
    f16* __restrict__ q2,                 // (4096,2048) hi|lo
    f16* __restrict__ X,                  // (4096,3072)
    f16* __restrict__ Y1,                 // (4096,2048)
    int* __restrict__ flags,              // 512 dense ints: [bx][wave]
    const float* __restrict__ nl,         // (32,512,1024) fp32
    f16* __restrict__ ctxT, f16* __restrict__ ctxN)
{
  __shared__ __align__(16) f16 whh_s[32][1032];
  __shared__ float partial[2][4][32][34];
  __shared__ float tile[32][33];
  const int tid = threadIdx.x;
  const int bx = blockIdx.x;

  if (bx >= 128) {
    // ---------------- nl transpose worker ----------------
    const int me = bx - 128;
    const int c = tid & 31, r = tid >> 5;
    for (int idx = me; idx < 16384; idx += 128) {
      int b = idx >> 9, rr2 = idx & 511;
      int l0 = (rr2 & 15) * 32, h0v = (rr2 >> 4) * 32;
      const float* inb = nl + (long)b * 512 * 1024;
      f16* oTb = ctxT + (long)b * 1024 * 512;
      f16* oNb = ctxN + (long)b * 512 * 1024;
#pragma unroll
      for (int p = 0; p < 4; ++p) {
        float v = inb[(long)(l0 + r + p*8) * 1024 + h0v + c];
        tile[r + p*8][c] = v;
        oNb[(long)(l0 + r + p*8) * 1024 + h0v + c] = (f16)v;
      }
      __syncthreads();
#pragma unroll
      for (int p = 0; p < 4; ++p)
        oTb[(long)(h0v + r + p*8) * 512 + l0 + c] = (f16)tile[c][r + p*8];
      __syncthreads();   // tile reused next iteration
    }
    return;
  }

  // ---------------- LSTM (identical to R3/R8/R9) ----------------
  const int w = tid >> 6, lane = tid & 63;
  const int lr = lane >> 4, lc = lane & 15;
  const int j0 = bx * 8;

  // stage Whh slice: LDS row r=(g*8+jj) <- global row g*1024 + j0 + jj
  for (int i = tid; i < 32 * 128; i += 256) {
    int r = i >> 7, c8 = i & 127;
    int g = r >> 3, jj = r & 7;
    *(uint4*)&whh_s[r][c8 * 8] =
        *(const uint4*)(Whh + ((long)g * 1024 + j0 + jj) * 1024 + c8 * 8);
  }
  const int b_own = tid >> 3, jj_own = tid & 7;
  const int j_own = j0 + jj_own;
  float c_reg = c0[(long)b_own * 1024 + j_own];
  float4 pg4 = *(const float4*)(prod_gates + (long)b_own * 4096 + j_own * 4);
  int nid0 = nt_ids[b_own];
  float4 nt4 = *(const float4*)(nt_table + (long)nid0 * 4096 + j_own * 4);
  __syncthreads();   // whh_s ready

  // hoist step-invariant B fragments LDS -> registers (whh_s dead afterwards)
  f16x8 B0[8], B1[8];
#pragma unroll
  for (int kt = 0; kt < 8; ++kt) {
    int k = w * 256 + kt * 32 + lr * 8;
    B0[kt] = *(const f16x8*)&whh_s[lc][k];
    B1[kt] = *(const f16x8*)&whh_s[16 + lc][k];
  }

  // A base: fragment kt of wave w = st[t][w*32+kt*4+lr][lc or 16+lc][0..8)
  const f16* pA = st + (long)(w * 32 + lr) * 256 + lc * 8;
  const int* fp = flags + w * 128 + lane * 2;   // this wave's 128 producer flags

  for (int t = 0; t < TT; ++t) {
    // ---- poll producer flags (tiny, coalesced) ----
    if (t > 0) {
      int done = 0;
      while (true) {
        if (!done) {
          i32x2 ff;
          asm volatile("global_load_dwordx2 %0, %1, off sc0 sc1\n\t"
                       "s_waitcnt vmcnt(0)"
                       : "=&v"(ff) : "v"(fp) : "memory");
          done = (ff.x >= t) & (ff.y >= t);
        }
        if (__all(done)) break;
        __builtin_amdgcn_s_sleep(1);
      }
    }

    // ---- single A-burst: 16 x dwordx4 sc0 sc1 ----
    u32x4 A0[8], A1[8];
    {
      const f16* pt = pA + (long)t * 32768;
#pragma unroll
      for (int q = 0; q < 4; ++q) {
        asm volatile(
          "global_load_dwordx4 %0, %4, off sc0 sc1\n\t"
          "global_load_dwordx4 %1, %4, off offset:256 sc0 sc1\n\t"
          "global_load_dwordx4 %2, %4, off offset:2048 sc0 sc1\n\t"
          "global_load_dwordx4 %3, %4, off offset:2304 sc0 sc1"
          : "=&v"(A0[2*q]), "=&v"(A1[2*q]), "=&v"(A0[2*q+1]), "=&v"(A1[2*q+1])
          : "v"(pt + (long)q * 2048) : "memory");
      }
      asm volatile("s_waitcnt vmcnt(0)" ::: "memory");
      __builtin_amdgcn_sched_barrier(0);   // no MFMA hoist above the waitcnt
    }

    // prefetch next step's nt gates (off the critical path)
    float4 nt4n = nt4;
    if (t + 1 < TT) {
      int nidn = nt_ids[(t + 1) * 32 + b_own];
      nt4n = *(const float4*)(nt_table + (long)nidn * 4096 + j_own * 4);
    }

    f32x4 acc[2][2];
#pragma unroll
    for (int i = 0; i < 2; ++i)
#pragma unroll
      for (int j = 0; j < 2; ++j) { f32x4 zz = {0.f,0.f,0.f,0.f}; acc[i][j] = zz; }
#pragma unroll
    for (int kt = 0; kt < 8; ++kt) {
      f16x8 a0v = __builtin_bit_cast(f16x8, A0[kt]);
      f16x8 a1v = __builtin_bit_cast(f16x8, A1[kt]);
      acc[0][0] = __builtin_amdgcn_mfma_f32_16x16x32_f16(a0v, B0[kt], acc[0][0], 0, 0, 0);
      acc[0][1] = __builtin_amdgcn_mfma_f32_16x16x32_f16(a0v, B1[kt], acc[0][1], 0, 0, 0);
      acc[1][0] = __builtin_amdgcn_mfma_f32_16x16x32_f16(a1v, B0[kt], acc[1][0], 0, 0, 0);
      acc[1][1] = __builtin_amdgcn_mfma_f32_16x16x32_f16(a1v, B1[kt], acc[1][1], 0, 0, 0);
    }
    float (*pp)[32][34] = partial[t & 1];
#pragma unroll
    for (int mi = 0; mi < 2; ++mi)
#pragma unroll
      for (int ni = 0; ni < 2; ++ni)
#pragma unroll
        for (int r = 0; r < 4; ++r)
          pp[w][ni * 16 + lc][mi * 16 + lr * 4 + r] = acc[mi][ni][r];
    __syncthreads();

    // reduce 4 K-slices + LSTM cell (double-buffered partial: no 2nd barrier)
    float g4[4];
#pragma unroll
    for (int g = 0; g < 4; ++g) {
      int rrow = g * 8 + jj_own;
      g4[g] = pp[0][rrow][b_own] + pp[1][rrow][b_own] +
              pp[2][rrow][b_own] + pp[3][rrow][b_own];
    }
    float ii = sigmoidf_(g4[0] + nt4.x + pg4.x);
    float ff = sigmoidf_(g4[1] + nt4.y + pg4.y);
    float gg = tanhf(g4[2] + nt4.z + pg4.z);
    float oo = sigmoidf_(g4[3] + nt4.w + pg4.w);
    c_reg = ff * c_reg + ii * gg;
    float hn = oo * tanhf(c_reg);
    f16 hi = (f16)hn;

    // ---- publish h_{t+1}: pack 8 halves -> one dwordx4 per group ----
    if (t + 1 < TT) {
      union { f16 h; unsigned short u; } cv; cv.h = hi;
      unsigned me2 = cv.u;
      unsigned d  = me2 | ((unsigned)__shfl_down((int)me2, 1) << 16);
      unsigned d2 = (unsigned)__shfl_down((int)d, 2);
      unsigned e0 = (unsigned)__shfl_down((int)d, 4);
      unsigned e1 = (unsigned)__shfl_down((int)d2, 4);
      if (jj_own == 0) {
        u32x4 pay; pay.x = d; pay.y = d2; pay.z = e0; pay.w = e1;
        f16* pst = st + (long)(t + 1) * 32768 + bx * 256 + b_own * 8;
        asm volatile("global_store_dwordx4 %0, %1, off sc0 sc1"
                     :: "v"(pst), "v"(pay) : "memory");
      }
      asm volatile("s_waitcnt vmcnt(0)" ::: "memory");   // data acked
      if (lane == 0) {
        int* myf = flags + bx * 4 + w;
        int fv = t + 1;
        asm volatile("global_store_dword %0, %1, off sc0 sc1"
                     :: "v"(myf), "v"(fv) : "memory");
      }
    }

    // non-critical stores: complete in the shadow of the next poll
    long row = (long)b_own * 128 + t;
    q2[row * 2048 + j_own]        = hi;
    q2[row * 2048 + 1024 + j_own] = (f16)(hn - (float)hi);
    X[row * 3072 + j_own]         = hi;
    Y1[row * 2048 + 1024 + j_own] = hi;

    nt4 = nt4n;
  }
}

// ---------------------------------------------------------------------------
// Row softmax over 512 cols of sum of 4 fp32 planes -> fp16. One block/row.
__global__ __launch_bounds__(256) void k_softmax4(const float* __restrict__ p,
                                                  long pstride,
                                                  f16* __restrict__ out) {
  long row = blockIdx.x;
  const float* p0 = p + row * 512;
  out += row * 512;
  const int tid = threadIdx.x, w = tid >> 6, lane = tid & 63;
  float vx = 0.f, vy = 0.f;
#pragma unroll
  for (int s = 0; s < 4; ++s) {
    float2 a = ((const float2*)(p0 + s * pstride))[tid];
    vx += a.x; vy += a.y;
  }
  float m = fmaxf(vx, vy);
#pragma unroll
  for (int off = 32; off; off >>= 1) m = fmaxf(m, __shfl_xor(m, off));
  __shared__ float red[8];
  if (lane == 0) red[w] = m;
  __syncthreads();
  m = fmaxf(fmaxf(red[0], red[1]), fmaxf(red[2], red[3]));
  float e0 = __expf(vx - m), e1 = __expf(vy - m);
  float s2 = e0 + e1;
#pragma unroll
  for (int off = 32; off; off >>= 1) s2 += __shfl_xor(s2, off);
  if (lane == 0) red[4 + w] = s2;
  __syncthreads();
  s2 = red[4] + red[5] + red[6] + red[7];
  float inv = 1.0f / s2;
  out[tid * 2]     = (f16)(e0 * inv);
  out[tid * 2 + 1] = (f16)(e1 * inv);
}

// ---------------------------------------------------------------------------
extern "C" void kernel_launch(void* const* d_in, const int* in_sizes, int n_in,
                              void* d_out, int out_size, void* d_ws, size_t ws_size,
                              hipStream_t stream)
{
  const int*   init_prod = (const int*)d_in[0];
  const int*   nt_ids    = (const int*)d_in[1];
  const float* h0   = (const float*)d_in[2];
  const float* c0   = (const float*)d_in[3];
  const float* nl   = (const float*)d_in[4];
  const float* env  = (const float*)d_in[5];
  const float* nt_emb   = (const float*)d_in[6];
  const float* rule_emb = (const float*)d_in[7];
  const float* W_ih = (const float*)d_in[8];
  const float* W_hh = (const float*)d_in[9];
  const float* b_ih = (const float*)d_in[10];
  const float* b_hh = (const float*)d_in[11];
  const float* Wz   = (const float*)d_in[12];
  const float* bz   = (const float*)d_in[13];
  const float* We   = (const float*)d_in[14];
  const float* be   = (const float*)d_in[15];
  const float* Wc   = (const float*)d_in[16];
  const float* bc   = (const float*)d_in[17];
  float* out = (float*)d_out;
  (void)in_sizes; (void)n_in; (void)out_size; (void)ws_size;

  size_t off = 0;
  auto carve = [&](size_t bytes) {
    char* p = (char*)d_ws + off;
    off += (bytes + 255) & ~(size_t)255;
    return (void*)p;
  };
  // Total carve ~209 MB -- the R3/R5/R8/R9 proven-safe workspace envelope.
  f16*   Whh_h   = (f16*)carve(4096L * 1024 * 2);
  f16*   Wz_h    = (f16*)carve(1024L * 2048 * 2);
  f16*   We_h    = (f16*)carve(1024L * 2048 * 2);
  f16*   Wc_h    = (f16*)carve(1024L * 3072 * 2);
  f16*   xcat    = (f16*)carve(232L * 2048 * 2);        // merged gate A operand
  float* nt_table = (float*)carve(232L * 4096 * 4);     // rows 200+ = prod_gates
  f16*   st_hi   = (f16*)carve(129L * 128 * 32 * 8 * 2);  // [t][bx][b][jj]
  f16*   q2      = (f16*)carve(4096L * 2048 * 2);   // query hi|lo (h, then zt)
  f16*   X       = (f16*)carve(4096L * 3072 * 2);   // [h | zt | et] for ct GEMM
  f16*   Y1      = (f16*)carve(4096L * 2048 * 2);   // [mix1 | h]  for zt GEMM
  f16*   Y2      = (f16*)carve(4096L * 2048 * 2);   // [mix2 | zt] for et GEMM
  f16*   ctx_h   = (f16*)carve(32L * 512 * 1024 * 2);   // shared nl->env
  f16*   ctxT    = (f16*)carve(32L * 1024 * 512 * 2);   // shared nl->env
  float* scoresP = (float*)carve(4L * 32 * 128 * 512 * 4);  // 4 split-K planes
  f16*   attn    = (f16*)carve(4096L * 512 * 2);
  int*   bar     = (int*)carve(2048);   // 512 dense flags
  f16*   Wih_h   = (f16*)X;   // alias: Wih dead before LSTM writes X

  // fused prep: converts + xcat build + h0 seed + flag zero (one launch)
  k_prep<<<dim3(8192), dim3(256), 0, stream>>>(
      W_ih, W_hh, Wz, We, Wc, nt_emb, rule_emb, init_prod, h0,
      Wih_h, Whh_h, Wz_h, We_h, Wc_h, xcat, st_hi, bar);

  auto gemm = [&](const f16* A, long lda, long sA,
                  const f16* B, long ldb, long sB,
                  float* oF, long ldF, long sF, long sSl,
                  f16* oH, long ldH, long sH,
                  f16* oH2, long ldH2, long sH2,
                  f16* o2, long ld2, long s2,
                  const float* b1, const float* b2,
                  int M, int N, int K, int act, int bmod, int zdiv, int ilv,
                  int batch, const float* tin, f16* tT, f16* tN, int brow0) {
    dim3 grid((unsigned)((M + 127) / 128), (unsigned)((N + 127) / 128),
              (unsigned)(batch * zdiv + (tin ? 1 : 0)));
    k_gemm<<<grid, dim3(256), 0, stream>>>(A, lda, sA, B, ldb, sB,
                                           oF, ldF, sF, sSl, oH, ldH, sH,
                                           oH2, ldH2, sH2, o2, ld2, s2,
                                           b1, b2, M, N, K, act, bmod, zdiv,
                                           ilv, tin, tT, tN, brow0);
  };
  const long SPL = 32L * 128 * 512;   // split-K plane stride (floats)

  // merged gate tables: [nte|0 ; 0|prod] @ W_ih^T, biases on rows >= 200
  gemm(xcat, 2048, 0, Wih_h, 2048, 0, nt_table, 4096, 0, 0,
       nullptr,0,0, nullptr,0,0, nullptr,0,0, b_ih, b_hh,
       232, 4096, 2048, 0, 0, 1, 1, 1, nullptr, nullptr, nullptr, 200);

  // persistent LSTM (blocks 0-127) + hidden nl transpose (blocks 128-255)
  k_lstm_all<<<dim3(256), dim3(256), 0, stream>>>(
      Whh_h, nt_table, nt_table + 200L * 4096, nt_ids, c0, st_hi, q2, X, Y1,
      bar, nl, ctxT, ctx_h);

  // --- attention over nl (ctx buffers filled by the fused LSTM kernel) ---
  gemm(q2, 2048, 128L * 2048, ctx_h, 1024, 512L * 1024,
       scoresP, 512, 128L * 512, SPL, nullptr,0,0, nullptr,0,0, nullptr,0,0,
       nullptr, nullptr, 128, 512, 2048, 0, 1024, 4, 0, 32,
       nullptr, nullptr, nullptr, 0);
  k_softmax4<<<dim3(4096), dim3(256), 0, stream>>>(scoresP, SPL, attn);
  gemm(attn, 512, 128L * 512, ctxT, 512, 1024L * 512,
       nullptr,0,0,0, Y1, 2048, 128L * 2048, nullptr,0,0, nullptr,0,0,
       nullptr, nullptr, 128, 1024, 512, 0, 0, 1, 0, 32,
       nullptr, nullptr, nullptr, 0);
  // zt = tanh(Y1 @ Wz^T + bz) -> X[:,1024:2048), Y2[:,1024:2048), q2
  //   + side-crew layer transposes env -> ctxT/ctx_h (both nl ctx dead here)
  gemm(Y1, 2048, 0, Wz_h, 2048, 0,
       nullptr,0,0,0, X + 1024, 3072, 0, Y2 + 1024, 2048, 0, q2, 2048, 0,
       bz, nullptr, 4096, 1024, 2048, 1, 0, 1, 0, 1,
       env, ctxT, ctx_h, 0);

  // --- attention over env (ctx buffers rewritten inside the zt launch) ---
  gemm(q2, 2048, 128L * 2048, ctx_h, 1024, 512L * 1024,
       scoresP, 512, 128L * 512, SPL, nullptr,0,0, nullptr,0,0, nullptr,0,0,
       nullptr, nullptr, 128, 512, 2048, 0, 1024, 4, 0, 32,
       nullptr, nullptr, nullptr, 0);
  k_softmax4<<<dim3(4096), dim3(256), 0, stream>>>(scoresP, SPL, attn);
  gemm(attn, 512, 128L * 512, ctxT, 512, 1024L * 512,
       nullptr,0,0,0, Y2, 2048, 128L * 2048, nullptr,0,0, nullptr,0,0,
       nullptr, nullptr, 128, 1024, 512, 0, 0, 1, 0, 32,
       nullptr, nullptr, nullptr, 0);
  // et = tanh(Y2 @ We^T + be) -> X[:,2048:3072)
  gemm(Y2, 2048, 0, We_h, 2048, 0,
       nullptr,0,0,0, X + 2048, 3072, 0, nullptr,0,0, nullptr,0,0,
       be, nullptr, 4096, 1024, 2048, 1, 0, 1, 0, 1,
       nullptr, nullptr, nullptr, 0);

  // --- ct = tanh(X=[h|zt|et] @ Wc^T + bc) -> d_out (T,B,H) ---
  gemm(X, 3072, 128L * 3072, Wc_h, 3072, 0,
       out, 32L * 1024, 1024, 0, nullptr,0,0, nullptr,0,0, nullptr,0,0,
       bc, nullptr, 128, 1024, 3072, 1, 0, 1, 0, 32,
       nullptr, nullptr, nullptr, 0);
}

// Round 11
// 1048.668 us; speedup vs baseline: 1.0490x; 1.0490x over previous
//
#include <hip/hip_runtime.h>
#include <hip/hip_bf16.h>

typedef _Float16 f16;
typedef __attribute__((ext_vector_type(8))) _Float16 f16x8;
typedef __attribute__((ext_vector_type(4))) float f32x4;
typedef __attribute__((ext_vector_type(4))) unsigned int u32x4;
typedef __attribute__((ext_vector_type(2))) int i32x2;

#define TT 128

__device__ __forceinline__ float sigmoidf_(float x) { return 1.0f / (1.0f + __expf(-x)); }

// ---------------------------------------------------------------------------
// Fused prep: weight converts + xcat build (gate-GEMM A operand) + h0 seed +
// flag zeroing in ONE launch.
__global__ __launch_bounds__(256) void k_prep(
    const float* __restrict__ W_ih, const float* __restrict__ W_hh,
    const float* __restrict__ Wz, const float* __restrict__ We,
    const float* __restrict__ Wc, const float* __restrict__ nt_emb,
    const float* __restrict__ rule_emb, const int* __restrict__ init_prod,
    const float* __restrict__ h0,
    f16* __restrict__ Wih_h, f16* __restrict__ Whh_h,
    f16* __restrict__ Wz_h, f16* __restrict__ We_h, f16* __restrict__ Wc_h,
    f16* __restrict__ xcat, f16* __restrict__ st, int* __restrict__ bar)
{
  const long nWih = 2097152, nWhh = 1048576, nWz = 524288, nWe = 524288,
             nWc = 786432;
  const long T0 = nWih, T1 = T0 + nWhh, T2 = T1 + nWz, T3 = T2 + nWe,
             T4 = T3 + nWc, T5 = T4 + 475136, T6 = T5 + 32768, T7 = T6 + 512;
  const long stride = (long)gridDim.x * 256;
  for (long i = (long)blockIdx.x * 256 + threadIdx.x; i < T7; i += stride) {
    if (i < T4) {              // float4 -> 4x f16 converts
      const float* src; f16* dst; long j;
      if (i < T0)      { src = W_ih; dst = Wih_h; j = i; }
      else if (i < T1) { src = W_hh; dst = Whh_h; j = i - T0; }
      else if (i < T2) { src = Wz;   dst = Wz_h;  j = i - T1; }
      else if (i < T3) { src = We;   dst = We_h;  j = i - T2; }
      else             { src = Wc;   dst = Wc_h;  j = i - T3; }
      float4 v = ((const float4*)src)[j];
      dst[j*4+0] = (f16)v.x; dst[j*4+1] = (f16)v.y;
      dst[j*4+2] = (f16)v.z; dst[j*4+3] = (f16)v.w;
    } else if (i < T5) {       // xcat build (232 x 2048)
      long j = i - T4; int row = (int)(j >> 11), col = (int)(j & 2047);
      float v = 0.f;
      if (row < 200) { if (col < 1024) v = nt_emb[(long)row * 1024 + col]; }
      else if (col >= 1024)
        v = rule_emb[(long)init_prod[row - 200] * 1024 + (col - 1024)];
      xcat[j] = (f16)v;
    } else if (i < T6) {       // h0 -> st slot 0 ([t][bx][b][jj] layout)
      long j = i - T5; int b = (int)(j >> 10), k = (int)(j & 1023);
      st[(long)(k >> 3) * 256 + b * 8 + (k & 7)] = (f16)h0[j];
    } else {                   // zero flags
      bar[i - T6] = 0;
    }
  }
}

// ---------------------------------------------------------------------------
// fp16 MFMA GEMM: C[M,N] = act( A[M,K] @ B[N,K]^T + bias1 + bias2 )
// 128xNC tile (NC=128 or 64), BK=32, register-prefetch double buffer.
// NC=64 halves the N-tile -> doubles blocks -> 2 blocks/CU for the
// N=1024-class tail GEMMs (they sat at 1 block/CU = 1 wave/SIMD: zero
// latency hiding; R10 showed the tail is GEMM-throughput-bound).
// bmod: B K-index wraps mod bmod. zdiv: split-K, partials at outF+slice*sSl.
// ilv: outF column remap col -> (col&1023)*4 + (col>>10)  (gate-interleave).
// brow0: biases applied only to rows >= brow0 (merged gate-table GEMM).
// tin/toutT/toutN: LAST gridDim.z layer transposes tin instead of GEMM work.
template<int NC>
__global__ __launch_bounds__(256) void k_gemm(
    const f16* __restrict__ A, long lda, long sA,
    const f16* __restrict__ B, long ldb, long sB,
    float* __restrict__ outF, long ldF, long sF, long sSl,
    f16* __restrict__ outH, long ldH, long sH,
    f16* __restrict__ outH2, long ldH2, long sH2,
    f16* __restrict__ out2, long ld2, long s2,
    const float* __restrict__ bias1, const float* __restrict__ bias2,
    int M, int N, int K, int act, int bmod, int zdiv, int ilv,
    const float* __restrict__ tin, f16* __restrict__ toutT,
    f16* __restrict__ toutN, int brow0)
{
  constexpr int NJ = NC / 32;       // j-tiles per wave (4 or 2)
  constexpr int NP = NC / 64;       // 64-row staging passes for B (2 or 1)
  __shared__ __align__(16) f16 As[128][40];
  __shared__ __align__(16) f16 Bs[NC][40];
  const int tid = threadIdx.x;

  if (tin && blockIdx.z == gridDim.z - 1) {
    // ---------------- transpose side-crew ----------------
    __shared__ float ttile[32][33];
    const int me = blockIdx.y * gridDim.x + blockIdx.x;
    const int nblk = gridDim.x * gridDim.y;
    const int c = tid & 31, r = tid >> 5;
    for (int idx = me; idx < 16384; idx += nblk) {
      int b = idx >> 9, rr2 = idx & 511;
      int l0 = (rr2 & 15) * 32, h0v = (rr2 >> 4) * 32;
      const float* inb = tin + (long)b * 512 * 1024;
      f16* oTb = toutT + (long)b * 1024 * 512;
      f16* oNb = toutN + (long)b * 512 * 1024;
#pragma unroll
      for (int p = 0; p < 4; ++p) {
        float v = inb[(long)(l0 + r + p*8) * 1024 + h0v + c];
        ttile[r + p*8][c] = v;
        oNb[(long)(l0 + r + p*8) * 1024 + h0v + c] = (f16)v;
      }
      __syncthreads();
#pragma unroll
      for (int p = 0; p < 4; ++p)
        oTb[(long)(h0v + r + p*8) * 512 + l0 + c] = (f16)ttile[c][r + p*8];
      __syncthreads();
    }
    return;
  }

  const int w = tid >> 6, lane = tid & 63;
  const int wm = (w & 1) * 64, wn = (w >> 1) * (NC / 2);
  const int lr = lane >> 4, lc = lane & 15;
  const long m0 = (long)blockIdx.x * 128;
  const long n0 = (long)blockIdx.y * NC;
  int z = blockIdx.z, batch = z, slice = 0, Ks = K;
  if (zdiv > 1) { batch = z / zdiv; slice = z - batch * zdiv; Ks = K / zdiv; }
  const long kbeg = (long)slice * Ks;
  A += (long)batch * sA;
  B += (long)batch * sB;

  const int rr = tid >> 2, sg = (tid & 3) * 8;
  const int nIt = Ks / 32;

  uint4 pa[2], pb[NP];
  {
    long k = kbeg;
    long kb = bmod ? (k & (bmod - 1)) : k;
#pragma unroll
    for (int p = 0; p < 2; ++p) {
      int row = p * 64 + rr;
      uint4 va = {0,0,0,0};
      if (m0 + row < M) va = *(const uint4*)(A + (m0 + row) * lda + k + sg);
      pa[p] = va;
    }
#pragma unroll
    for (int p = 0; p < NP; ++p) {
      int row = p * 64 + rr;
      uint4 vb = {0,0,0,0};
      if (n0 + row < N) vb = *(const uint4*)(B + (n0 + row) * ldb + kb + sg);
      pb[p] = vb;
    }
  }

  f32x4 acc[4][NJ];
#pragma unroll
  for (int i = 0; i < 4; ++i)
#pragma unroll
    for (int j = 0; j < NJ; ++j) { f32x4 zz = {0.f,0.f,0.f,0.f}; acc[i][j] = zz; }

  for (int it = 0; it < nIt; ++it) {
#pragma unroll
    for (int p = 0; p < 2; ++p) *(uint4*)&As[p * 64 + rr][sg] = pa[p];
#pragma unroll
    for (int p = 0; p < NP; ++p) *(uint4*)&Bs[p * 64 + rr][sg] = pb[p];
    __syncthreads();
    if (it + 1 < nIt) {
      long k = kbeg + (long)(it + 1) * 32;
      long kb = bmod ? (k & (bmod - 1)) : k;
#pragma unroll
      for (int p = 0; p < 2; ++p) {
        int row = p * 64 + rr;
        uint4 va = {0,0,0,0};
        if (m0 + row < M) va = *(const uint4*)(A + (m0 + row) * lda + k + sg);
        pa[p] = va;
      }
#pragma unroll
      for (int p = 0; p < NP; ++p) {
        int row = p * 64 + rr;
        uint4 vb = {0,0,0,0};
        if (n0 + row < N) vb = *(const uint4*)(B + (n0 + row) * ldb + kb + sg);
        pb[p] = vb;
      }
    }
    f16x8 af[4], bf[NJ];
#pragma unroll
    for (int i = 0; i < 4; ++i) af[i] = *(const f16x8*)&As[wm + i*16 + lc][lr * 8];
#pragma unroll
    for (int j = 0; j < NJ; ++j) bf[j] = *(const f16x8*)&Bs[wn + j*16 + lc][lr * 8];
#pragma unroll
    for (int i = 0; i < 4; ++i)
#pragma unroll
      for (int j = 0; j < NJ; ++j)
        acc[i][j] = __builtin_amdgcn_mfma_f32_16x16x32_f16(af[i], bf[j], acc[i][j], 0, 0, 0);
    __syncthreads();
  }

  if (outF)  outF  += (long)batch * sF + (long)slice * sSl;
  if (outH)  outH  += (long)batch * sH;
  if (outH2) outH2 += (long)batch * sH2;
  if (out2)  out2  += (long)batch * s2;
#pragma unroll
  for (int i = 0; i < 4; ++i)
#pragma unroll
    for (int j = 0; j < NJ; ++j)
#pragma unroll
      for (int r = 0; r < 4; ++r) {
        long row = m0 + wm + i * 16 + lr * 4 + r;
        long col = n0 + wn + j * 16 + lc;
        if (row < M && col < N) {
          float v = acc[i][j][r];
          if (row >= brow0) {
            if (bias1) v += bias1[col];
            if (bias2) v += bias2[col];
          }
          if (act)   v = tanhf(v);
          if (outF) {
            long fc = ilv ? ((col & 1023) * 4 + (col >> 10)) : col;
            outF[row * ldF + fc] = v;
          }
          if (outH)  outH[row * ldH + col] = (f16)v;
          if (outH2) outH2[row * ldH2 + col] = (f16)v;
          if (out2) {
            f16 hi = (f16)v;
            out2[row * ld2 + col]        = hi;
            out2[row * ld2 + 1024 + col] = (f16)(v - (float)hi);
          }
        }
      }
}

// ---------------------------------------------------------------------------
// Persistent LSTM (R3-proven flag-gated dataflow) + hidden NL transpose.
// 256 blocks x 256 threads, 1 block/CU:
//   blocks 0..127:  the R3 LSTM (verified 495-504us across R3/R8/R9/R10).
//   blocks 128..255: transpose nl -> ctxT/ctx_h on the otherwise-idle half.
__global__ __launch_bounds__(256) void k_lstm_all(
    const f16* __restrict__ Whh,          // (4096,1024)
    const float* __restrict__ nt_table,   // (232,1024,4) gate-interleaved
    const float* __restrict__ prod_gates, // rows 200+ of nt_table
    const int* __restrict__ nt_ids,       // (128,32)
    const float* __restrict__ c0,         // (32,1024)
    f16* __restrict__ st,                 // (129,128,32,8) step/block-major
    f16* __restrict__ q2,                 // (4096,2048) hi|lo
    f16* __restrict__ X,                  // (4096,3072)
    f16* __restrict__ Y1,                 // (4096,2048)
    int* __restrict__ flags,              // 512 dense ints: [bx][wave]
    const float* __restrict__ nl,         // (32,512,1024) fp32
    f16* __restrict__ ctxT, f16* __restrict__ ctxN)
{
  __shared__ __align__(16) f16 whh_s[32][1032];
  __shared__ float partial[2][4][32][34];
  __shared__ float tile[32][33];
  const int tid = threadIdx.x;
  const int bx = blockIdx.x;

  if (bx >= 128) {
    // ---------------- nl transpose worker ----------------
    const int me = bx - 128;
    const int c = tid & 31, r = tid >> 5;
    for (int idx = me; idx < 16384; idx += 128) {
      int b = idx >> 9, rr2 = idx & 511;
      int l0 = (rr2 & 15) * 32, h0v = (rr2 >> 4) * 32;
      const float* inb = nl + (long)b * 512 * 1024;
      f16* oTb = ctxT + (long)b * 1024 * 512;
      f16* oNb = ctxN + (long)b * 512 * 1024;
#pragma unroll
      for (int p = 0; p < 4; ++p) {
        float v = inb[(long)(l0 + r + p*8) * 1024 + h0v + c];
        tile[r + p*8][c] = v;
        oNb[(long)(l0 + r + p*8) * 1024 + h0v + c] = (f16)v;
      }
      __syncthreads();
#pragma unroll
      for (int p = 0; p < 4; ++p)
        oTb[(long)(h0v + r + p*8) * 512 + l0 + c] = (f16)tile[c][r + p*8];
      __syncthreads();   // tile reused next iteration
    }
    return;
  }

  // ---------------- LSTM (identical to R3/R8/R9/R10) ----------------
  const int w = tid >> 6, lane = tid & 63;
  const int lr = lane >> 4, lc = lane & 15;
  const int j0 = bx * 8;

  // stage Whh slice: LDS row r=(g*8+jj) <- global row g*1024 + j0 + jj
  for (int i = tid; i < 32 * 128; i += 256) {
    int r = i >> 7, c8 = i & 127;
    int g = r >> 3, jj = r & 7;
    *(uint4*)&whh_s[r][c8 * 8] =
        *(const uint4*)(Whh + ((long)g * 1024 + j0 + jj) * 1024 + c8 * 8);
  }
  const int b_own = tid >> 3, jj_own = tid & 7;
  const int j_own = j0 + jj_own;
  float c_reg = c0[(long)b_own * 1024 + j_own];
  float4 pg4 = *(const float4*)(prod_gates + (long)b_own * 4096 + j_own * 4);
  int nid0 = nt_ids[b_own];
  float4 nt4 = *(const float4*)(nt_table + (long)nid0 * 4096 + j_own * 4);
  __syncthreads();   // whh_s ready

  // hoist step-invariant B fragments LDS -> registers (whh_s dead afterwards)
  f16x8 B0[8], B1[8];
#pragma unroll
  for (int kt = 0; kt < 8; ++kt) {
    int k = w * 256 + kt * 32 + lr * 8;
    B0[kt] = *(const f16x8*)&whh_s[lc][k];
    B1[kt] = *(const f16x8*)&whh_s[16 + lc][k];
  }

  // A base: fragment kt of wave w = st[t][w*32+kt*4+lr][lc or 16+lc][0..8)
  const f16* pA = st + (long)(w * 32 + lr) * 256 + lc * 8;
  const int* fp = flags + w * 128 + lane * 2;   // this wave's 128 producer flags

  for (int t = 0; t < TT; ++t) {
    // ---- poll producer flags (tiny, coalesced) ----
    if (t > 0) {
      int done = 0;
      while (true) {
        if (!done) {
          i32x2 ff;
          asm volatile("global_load_dwordx2 %0, %1, off sc0 sc1\n\t"
                       "s_waitcnt vmcnt(0)"
                       : "=&v"(ff) : "v"(fp) : "memory");
          done = (ff.x >= t) & (ff.y >= t);
        }
        if (__all(done)) break;
        __builtin_amdgcn_s_sleep(1);
      }
    }

    // ---- single A-burst: 16 x dwordx4 sc0 sc1 ----
    u32x4 A0[8], A1[8];
    {
      const f16* pt = pA + (long)t * 32768;
#pragma unroll
      for (int q = 0; q < 4; ++q) {
        asm volatile(
          "global_load_dwordx4 %0, %4, off sc0 sc1\n\t"
          "global_load_dwordx4 %1, %4, off offset:256 sc0 sc1\n\t"
          "global_load_dwordx4 %2, %4, off offset:2048 sc0 sc1\n\t"
          "global_load_dwordx4 %3, %4, off offset:2304 sc0 sc1"
          : "=&v"(A0[2*q]), "=&v"(A1[2*q]), "=&v"(A0[2*q+1]), "=&v"(A1[2*q+1])
          : "v"(pt + (long)q * 2048) : "memory");
      }
      asm volatile("s_waitcnt vmcnt(0)" ::: "memory");
      __builtin_amdgcn_sched_barrier(0);   // no MFMA hoist above the waitcnt
    }

    // prefetch next step's nt gates (off the critical path)
    float4 nt4n = nt4;
    if (t + 1 < TT) {
      int nidn = nt_ids[(t + 1) * 32 + b_own];
      nt4n = *(const float4*)(nt_table + (long)nidn * 4096 + j_own * 4);
    }

    f32x4 acc[2][2];
#pragma unroll
    for (int i = 0; i < 2; ++i)
#pragma unroll
      for (int j = 0; j < 2; ++j) { f32x4 zz = {0.f,0.f,0.f,0.f}; acc[i][j] = zz; }
#pragma unroll
    for (int kt = 0; kt < 8; ++kt) {
      f16x8 a0v = __builtin_bit_cast(f16x8, A0[kt]);
      f16x8 a1v = __builtin_bit_cast(f16x8, A1[kt]);
      acc[0][0] = __builtin_amdgcn_mfma_f32_16x16x32_f16(a0v, B0[kt], acc[0][0], 0, 0, 0);
      acc[0][1] = __builtin_amdgcn_mfma_f32_16x16x32_f16(a0v, B1[kt], acc[0][1], 0, 0, 0);
      acc[1][0] = __builtin_amdgcn_mfma_f32_16x16x32_f16(a1v, B0[kt], acc[1][0], 0, 0, 0);
      acc[1][1] = __builtin_amdgcn_mfma_f32_16x16x32_f16(a1v, B1[kt], acc[1][1], 0, 0, 0);
    }
    float (*pp)[32][34] = partial[t & 1];
#pragma unroll
    for (int mi = 0; mi < 2; ++mi)
#pragma unroll
      for (int ni = 0; ni < 2; ++ni)
#pragma unroll
        for (int r = 0; r < 4; ++r)
          pp[w][ni * 16 + lc][mi * 16 + lr * 4 + r] = acc[mi][ni][r];
    __syncthreads();

    // reduce 4 K-slices + LSTM cell (double-buffered partial: no 2nd barrier)
    float g4[4];
#pragma unroll
    for (int g = 0; g < 4; ++g) {
      int rrow = g * 8 + jj_own;
      g4[g] = pp[0][rrow][b_own] + pp[1][rrow][b_own] +
              pp[2][rrow][b_own] + pp[3][rrow][b_own];
    }
    float ii = sigmoidf_(g4[0] + nt4.x + pg4.x);
    float ff = sigmoidf_(g4[1] + nt4.y + pg4.y);
    float gg = tanhf(g4[2] + nt4.z + pg4.z);
    float oo = sigmoidf_(g4[3] + nt4.w + pg4.w);
    c_reg = ff * c_reg + ii * gg;
    float hn = oo * tanhf(c_reg);
    f16 hi = (f16)hn;

    // ---- publish h_{t+1}: pack 8 halves -> one dwordx4 per group ----
    if (t + 1 < TT) {
      union { f16 h; unsigned short u; } cv; cv.h = hi;
      unsigned me2 = cv.u;
      unsigned d  = me2 | ((unsigned)__shfl_down((int)me2, 1) << 16);
      unsigned d2 = (unsigned)__shfl_down((int)d, 2);
      unsigned e0 = (unsigned)__shfl_down((int)d, 4);
      unsigned e1 = (unsigned)__shfl_down((int)d2, 4);
      if (jj_own == 0) {
        u32x4 pay; pay.x = d; pay.y = d2; pay.z = e0; pay.w = e1;
        f16* pst = st + (long)(t + 1) * 32768 + bx * 256 + b_own * 8;
        asm volatile("global_store_dwordx4 %0, %1, off sc0 sc1"
                     :: "v"(pst), "v"(pay) : "memory");
      }
      asm volatile("s_waitcnt vmcnt(0)" ::: "memory");   // data acked
      if (lane == 0) {
        int* myf = flags + bx * 4 + w;
        int fv = t + 1;
        asm volatile("global_store_dword %0, %1, off sc0 sc1"
                     :: "v"(myf), "v"(fv) : "memory");
      }
    }

    // non-critical stores: complete in the shadow of the next poll
    long row = (long)b_own * 128 + t;
    q2[row * 2048 + j_own]        = hi;
    q2[row * 2048 + 1024 + j_own] = (f16)(hn - (float)hi);
    X[row * 3072 + j_own]         = hi;
    Y1[row * 2048 + 1024 + j_own] = hi;

    nt4 = nt4n;
  }
}

// ---------------------------------------------------------------------------
// Row softmax over 512 cols of sum of 4 fp32 planes -> fp16. One block/row.
__global__ __launch_bounds__(256) void k_softmax4(const float* __restrict__ p,
                                                  long pstride,
                                                  f16* __restrict__ out) {
  long row = blockIdx.x;
  const float* p0 = p + row * 512;
  out += row * 512;
  const int tid = threadIdx.x, w = tid >> 6, lane = tid & 63;
  float vx = 0.f, vy = 0.f;
#pragma unroll
  for (int s = 0; s < 4; ++s) {
    float2 a = ((const float2*)(p0 + s * pstride))[tid];
    vx += a.x; vy += a.y;
  }
  float m = fmaxf(vx, vy);
#pragma unroll
  for (int off = 32; off; off >>= 1) m = fmaxf(m, __shfl_xor(m, off));
  __shared__ float red[8];
  if (lane == 0) red[w] = m;
  __syncthreads();
  m = fmaxf(fmaxf(red[0], red[1]), fmaxf(red[2], red[3]));
  float e0 = __expf(vx - m), e1 = __expf(vy - m);
  float s2 = e0 + e1;
#pragma unroll
  for (int off = 32; off; off >>= 1) s2 += __shfl_xor(s2, off);
  if (lane == 0) red[4 + w] = s2;
  __syncthreads();
  s2 = red[4] + red[5] + red[6] + red[7];
  float inv = 1.0f / s2;
  out[tid * 2]     = (f16)(e0 * inv);
  out[tid * 2 + 1] = (f16)(e1 * inv);
}

// ---------------------------------------------------------------------------
extern "C" void kernel_launch(void* const* d_in, const int* in_sizes, int n_in,
                              void* d_out, int out_size, void* d_ws, size_t ws_size,
                              hipStream_t stream)
{
  const int*   init_prod = (const int*)d_in[0];
  const int*   nt_ids    = (const int*)d_in[1];
  const float* h0   = (const float*)d_in[2];
  const float* c0   = (const float*)d_in[3];
  const float* nl   = (const float*)d_in[4];
  const float* env  = (const float*)d_in[5];
  const float* nt_emb   = (const float*)d_in[6];
  const float* rule_emb = (const float*)d_in[7];
  const float* W_ih = (const float*)d_in[8];
  const float* W_hh = (const float*)d_in[9];
  const float* b_ih = (const float*)d_in[10];
  const float* b_hh = (const float*)d_in[11];
  const float* Wz   = (const float*)d_in[12];
  const float* bz   = (const float*)d_in[13];
  const float* We   = (const float*)d_in[14];
  const float* be   = (const float*)d_in[15];
  const float* Wc   = (const float*)d_in[16];
  const float* bc   = (const float*)d_in[17];
  float* out = (float*)d_out;
  (void)in_sizes; (void)n_in; (void)out_size; (void)ws_size;

  size_t off = 0;
  auto carve = [&](size_t bytes) {
    char* p = (char*)d_ws + off;
    off += (bytes + 255) & ~(size_t)255;
    return (void*)p;
  };
  // Total carve ~209 MB -- the R3/R5/R8/R9 proven-safe workspace envelope.
  f16*   Whh_h   = (f16*)carve(4096L * 1024 * 2);
  f16*   Wz_h    = (f16*)carve(1024L * 2048 * 2);
  f16*   We_h    = (f16*)carve(1024L * 2048 * 2);
  f16*   Wc_h    = (f16*)carve(1024L * 3072 * 2);
  f16*   xcat    = (f16*)carve(232L * 2048 * 2);        // merged gate A operand
  float* nt_table = (float*)carve(232L * 4096 * 4);     // rows 200+ = prod_gates
  f16*   st_hi   = (f16*)carve(129L * 128 * 32 * 8 * 2);  // [t][bx][b][jj]
  f16*   q2      = (f16*)carve(4096L * 2048 * 2);   // query hi|lo (h, then zt)
  f16*   X       = (f16*)carve(4096L * 3072 * 2);   // [h | zt | et] for ct GEMM
  f16*   Y1      = (f16*)carve(4096L * 2048 * 2);   // [mix1 | h]  for zt GEMM
  f16*   Y2      = (f16*)carve(4096L * 2048 * 2);   // [mix2 | zt] for et GEMM
  f16*   ctx_h   = (f16*)carve(32L * 512 * 1024 * 2);   // shared nl->env
  f16*   ctxT    = (f16*)carve(32L * 1024 * 512 * 2);   // shared nl->env
  float* scoresP = (float*)carve(4L * 32 * 128 * 512 * 4);  // 4 split-K planes
  f16*   attn    = (f16*)carve(4096L * 512 * 2);
  int*   bar     = (int*)carve(2048);   // 512 dense flags
  f16*   Wih_h   = (f16*)X;   // alias: Wih dead before LSTM writes X

  // fused prep: converts + xcat build + h0 seed + flag zero (one launch)
  k_prep<<<dim3(8192), dim3(256), 0, stream>>>(
      W_ih, W_hh, Wz, We, Wc, nt_emb, rule_emb, init_prod, h0,
      Wih_h, Whh_h, Wz_h, We_h, Wc_h, xcat, st_hi, bar);

  auto gemm = [&](const f16* A, long lda, long sA,
                  const f16* B, long ldb, long sB,
                  float* oF, long ldF, long sF, long sSl,
                  f16* oH, long ldH, long sH,
                  f16* oH2, long ldH2, long sH2,
                  f16* o2, long ld2, long s2,
                  const float* b1, const float* b2,
                  int M, int N, int K, int act, int bmod, int zdiv, int ilv,
                  int batch, const float* tin, f16* tT, f16* tN, int brow0,
                  int ncols) {
    dim3 grid((unsigned)((M + 127) / 128), (unsigned)((N + ncols - 1) / ncols),
              (unsigned)(batch * zdiv + (tin ? 1 : 0)));
    if (ncols == 64)
      k_gemm<64><<<grid, dim3(256), 0, stream>>>(A, lda, sA, B, ldb, sB,
                                                 oF, ldF, sF, sSl, oH, ldH, sH,
                                                 oH2, ldH2, sH2, o2, ld2, s2,
                                                 b1, b2, M, N, K, act, bmod,
                                                 zdiv, ilv, tin, tT, tN, brow0);
    else
      k_gemm<128><<<grid, dim3(256), 0, stream>>>(A, lda, sA, B, ldb, sB,
                                                  oF, ldF, sF, sSl, oH, ldH, sH,
                                                  oH2, ldH2, sH2, o2, ld2, s2,
                                                  b1, b2, M, N, K, act, bmod,
                                                  zdiv, ilv, tin, tT, tN, brow0);
  };
  const long SPL = 32L * 128 * 512;   // split-K plane stride (floats)

  // merged gate tables: [nte|0 ; 0|prod] @ W_ih^T, biases on rows >= 200
  gemm(xcat, 2048, 0, Wih_h, 2048, 0, nt_table, 4096, 0, 0,
       nullptr,0,0, nullptr,0,0, nullptr,0,0, b_ih, b_hh,
       232, 4096, 2048, 0, 0, 1, 1, 1, nullptr, nullptr, nullptr, 200, 128);

  // persistent LSTM (blocks 0-127) + hidden nl transpose (blocks 128-255)
  k_lstm_all<<<dim3(256), dim3(256), 0, stream>>>(
      Whh_h, nt_table, nt_table + 200L * 4096, nt_ids, c0, st_hi, q2, X, Y1,
      bar, nl, ctxT, ctx_h);

  // --- attention over nl (ctx buffers filled by the fused LSTM kernel) ---
  gemm(q2, 2048, 128L * 2048, ctx_h, 1024, 512L * 1024,
       scoresP, 512, 128L * 512, SPL, nullptr,0,0, nullptr,0,0, nullptr,0,0,
       nullptr, nullptr, 128, 512, 2048, 0, 1024, 4, 0, 32,
       nullptr, nullptr, nullptr, 0, 128);
  k_softmax4<<<dim3(4096), dim3(256), 0, stream>>>(scoresP, SPL, attn);
  gemm(attn, 512, 128L * 512, ctxT, 512, 1024L * 512,
       nullptr,0,0,0, Y1, 2048, 128L * 2048, nullptr,0,0, nullptr,0,0,
       nullptr, nullptr, 128, 1024, 512, 0, 0, 1, 0, 32,
       nullptr, nullptr, nullptr, 0, 64);
  // zt = tanh(Y1 @ Wz^T + bz) -> X[:,1024:2048), Y2[:,1024:2048), q2
  //   + side-crew layer transposes env -> ctxT/ctx_h (both nl ctx dead here)
  gemm(Y1, 2048, 0, Wz_h, 2048, 0,
       nullptr,0,0,0, X + 1024, 3072, 0, Y2 + 1024, 2048, 0, q2, 2048, 0,
       bz, nullptr, 4096, 1024, 2048, 1, 0, 1, 0, 1,
       env, ctxT, ctx_h, 0, 64);

  // --- attention over env (ctx buffers rewritten inside the zt launch) ---
  gemm(q2, 2048, 128L * 2048, ctx_h, 1024, 512L * 1024,
       scoresP, 512, 128L * 512, SPL, nullptr,0,0, nullptr,0,0, nullptr,0,0,
       nullptr, nullptr, 128, 512, 2048, 0, 1024, 4, 0, 32,
       nullptr, nullptr, nullptr, 0, 128);
  k_softmax4<<<dim3(4096), dim3(256), 0, stream>>>(scoresP, SPL, attn);
  gemm(attn, 512, 128L * 512, ctxT, 512, 1024L * 512,
       nullptr,0,0,0, Y2, 2048, 128L * 2048, nullptr,0,0, nullptr,0,0,
       nullptr, nullptr, 128, 1024, 512, 0, 0, 1, 0, 32,
       nullptr, nullptr, nullptr, 0, 64);
  // et = tanh(Y2 @ We^T + be) -> X[:,2048:3072)
  gemm(Y2, 2048, 0, We_h, 2048, 0,
       nullptr,0,0,0, X + 2048, 3072, 0, nullptr,0,0, nullptr,0,0,
       be, nullptr, 4096, 1024, 2048, 1, 0, 1, 0, 1,
       nullptr, nullptr, nullptr, 0, 64);

  // --- ct = tanh(X=[h|zt|et] @ Wc^T + bc) -> d_out (T,B,H) ---
  gemm(X, 3072, 128L * 3072, Wc_h, 3072, 0,
       out, 32L * 1024, 1024, 0, nullptr,0,0, nullptr,0,0, nullptr,0,0,
       bc, nullptr, 128, 1024, 3072, 1, 0, 1, 0, 32,
       nullptr, nullptr, nullptr, 0, 64);
}

// Round 12
// 999.756 us; speedup vs baseline: 1.1003x; 1.0489x over previous
//
#include <hip/hip_runtime.h>
#include <hip/hip_bf16.h>

typedef _Float16 f16;
typedef __attribute__((ext_vector_type(8))) _Float16 f16x8;
typedef __attribute__((ext_vector_type(4))) float f32x4;
typedef __attribute__((ext_vector_type(4))) unsigned int u32x4;
typedef __attribute__((ext_vector_type(2))) int i32x2;

#define TT 128

__device__ __forceinline__ float sigmoidf_(float x) { return 1.0f / (1.0f + __expf(-x)); }

// ---------------------------------------------------------------------------
// Fused prep: weight converts + xcat build + h0 seed + st POISON (slots
// 1..128 <- 0xFFFF halves; f16 -NaN, unproducible by the tanh cell path) +
// flag zeroing in ONE launch.
__global__ __launch_bounds__(256) void k_prep(
    const float* __restrict__ W_ih, const float* __restrict__ W_hh,
    const float* __restrict__ Wz, const float* __restrict__ We,
    const float* __restrict__ Wc, const float* __restrict__ nt_emb,
    const float* __restrict__ rule_emb, const int* __restrict__ init_prod,
    const float* __restrict__ h0,
    f16* __restrict__ Wih_h, f16* __restrict__ Whh_h,
    f16* __restrict__ Wz_h, f16* __restrict__ We_h, f16* __restrict__ Wc_h,
    f16* __restrict__ xcat, f16* __restrict__ st, int* __restrict__ bar)
{
  const long nWih = 2097152, nWhh = 1048576, nWz = 524288, nWe = 524288,
             nWc = 786432;
  const long T0 = nWih, T1 = T0 + nWhh, T2 = T1 + nWz, T3 = T2 + nWe,
             T4 = T3 + nWc, T5 = T4 + 475136, T6 = T5 + 32768,
             T6p = T6 + 2097152, T7 = T6p + 512;
  const long stride = (long)gridDim.x * 256;
  for (long i = (long)blockIdx.x * 256 + threadIdx.x; i < T7; i += stride) {
    if (i < T4) {              // float4 -> 4x f16 converts
      const float* src; f16* dst; long j;
      if (i < T0)      { src = W_ih; dst = Wih_h; j = i; }
      else if (i < T1) { src = W_hh; dst = Whh_h; j = i - T0; }
      else if (i < T2) { src = Wz;   dst = Wz_h;  j = i - T1; }
      else if (i < T3) { src = We;   dst = We_h;  j = i - T2; }
      else             { src = Wc;   dst = Wc_h;  j = i - T3; }
      float4 v = ((const float4*)src)[j];
      dst[j*4+0] = (f16)v.x; dst[j*4+1] = (f16)v.y;
      dst[j*4+2] = (f16)v.z; dst[j*4+3] = (f16)v.w;
    } else if (i < T5) {       // xcat build (232 x 2048)
      long j = i - T4; int row = (int)(j >> 11), col = (int)(j & 2047);
      float v = 0.f;
      if (row < 200) { if (col < 1024) v = nt_emb[(long)row * 1024 + col]; }
      else if (col >= 1024)
        v = rule_emb[(long)init_prod[row - 200] * 1024 + (col - 1024)];
      xcat[j] = (f16)v;
    } else if (i < T6) {       // h0 -> st slot 0 ([t][bx][b][jj] layout)
      long j = i - T5; int b = (int)(j >> 10), k = (int)(j & 1023);
      st[(long)(k >> 3) * 256 + b * 8 + (k & 7)] = (f16)h0[j];
    } else if (i < T6p) {      // poison st slots 1..128 (dwords)
      ((unsigned int*)st)[16384 + (i - T6)] = 0xFFFFFFFFu;
    } else {                   // zero flags
      bar[i - T6p] = 0;
    }
  }
}

// ---------------------------------------------------------------------------
// fp16 MFMA GEMM: C[M,N] = act( A[M,K] @ B[N,K]^T + bias1 + bias2 )
// 128xNC tile (NC=128 or 64), BK=32, register-prefetch double buffer.
// NC=64 -> 2 blocks/CU for the N=1024-class tail GEMMs (R11: +51us).
// bmod: B K-index wraps mod bmod. zdiv: split-K, partials at outF+slice*sSl.
// ilv: outF column remap col -> (col&1023)*4 + (col>>10)  (gate-interleave).
// brow0: biases applied only to rows >= brow0 (merged gate-table GEMM).
// tin/toutT/toutN: LAST gridDim.z layer transposes tin instead of GEMM work.
template<int NC>
__global__ __launch_bounds__(256) void k_gemm(
    const f16* __restrict__ A, long lda, long sA,
    const f16* __restrict__ B, long ldb, long sB,
    float* __restrict__ outF, long ldF, long sF, long sSl,
    f16* __restrict__ outH, long ldH, long sH,
    f16* __restrict__ outH2, long ldH2, long sH2,
    f16* __restrict__ out2, long ld2, long s2,
    const float* __restrict__ bias1, const float* __restrict__ bias2,
    int M, int N, int K, int act, int bmod, int zdiv, int ilv,
    const float* __restrict__ tin, f16* __restrict__ toutT,
    f16* __restrict__ toutN, int brow0)
{
  constexpr int NJ = NC / 32;       // j-tiles per wave (4 or 2)
  constexpr int NP = NC / 64;       // 64-row staging passes for B (2 or 1)
  __shared__ __align__(16) f16 As[128][40];
  __shared__ __align__(16) f16 Bs[NC][40];
  const int tid = threadIdx.x;

  if (tin && blockIdx.z == gridDim.z - 1) {
    // ---------------- transpose side-crew ----------------
    __shared__ float ttile[32][33];
    const int me = blockIdx.y * gridDim.x + blockIdx.x;
    const int nblk = gridDim.x * gridDim.y;
    const int c = tid & 31, r = tid >> 5;
    for (int idx = me; idx < 16384; idx += nblk) {
      int b = idx >> 9, rr2 = idx & 511;
      int l0 = (rr2 & 15) * 32, h0v = (rr2 >> 4) * 32;
      const float* inb = tin + (long)b * 512 * 1024;
      f16* oTb = toutT + (long)b * 1024 * 512;
      f16* oNb = toutN + (long)b * 512 * 1024;
#pragma unroll
      for (int p = 0; p < 4; ++p) {
        float v = inb[(long)(l0 + r + p*8) * 1024 + h0v + c];
        ttile[r + p*8][c] = v;
        oNb[(long)(l0 + r + p*8) * 1024 + h0v + c] = (f16)v;
      }
      __syncthreads();
#pragma unroll
      for (int p = 0; p < 4; ++p)
        oTb[(long)(h0v + r + p*8) * 512 + l0 + c] = (f16)ttile[c][r + p*8];
      __syncthreads();
    }
    return;
  }

  const int w = tid >> 6, lane = tid & 63;
  const int wm = (w & 1) * 64, wn = (w >> 1) * (NC / 2);
  const int lr = lane >> 4, lc = lane & 15;
  const long m0 = (long)blockIdx.x * 128;
  const long n0 = (long)blockIdx.y * NC;
  int z = blockIdx.z, batch = z, slice = 0, Ks = K;
  if (zdiv > 1) { batch = z / zdiv; slice = z - batch * zdiv; Ks = K / zdiv; }
  const long kbeg = (long)slice * Ks;
  A += (long)batch * sA;
  B += (long)batch * sB;

  const int rr = tid >> 2, sg = (tid & 3) * 8;
  const int nIt = Ks / 32;

  uint4 pa[2], pb[NP];
  {
    long k = kbeg;
    long kb = bmod ? (k & (bmod - 1)) : k;
#pragma unroll
    for (int p = 0; p < 2; ++p) {
      int row = p * 64 + rr;
      uint4 va = {0,0,0,0};
      if (m0 + row < M) va = *(const uint4*)(A + (m0 + row) * lda + k + sg);
      pa[p] = va;
    }
#pragma unroll
    for (int p = 0; p < NP; ++p) {
      int row = p * 64 + rr;
      uint4 vb = {0,0,0,0};
      if (n0 + row < N) vb = *(const uint4*)(B + (n0 + row) * ldb + kb + sg);
      pb[p] = vb;
    }
  }

  f32x4 acc[4][NJ];
#pragma unroll
  for (int i = 0; i < 4; ++i)
#pragma unroll
    for (int j = 0; j < NJ; ++j) { f32x4 zz = {0.f,0.f,0.f,0.f}; acc[i][j] = zz; }

  for (int it = 0; it < nIt; ++it) {
#pragma unroll
    for (int p = 0; p < 2; ++p) *(uint4*)&As[p * 64 + rr][sg] = pa[p];
#pragma unroll
    for (int p = 0; p < NP; ++p) *(uint4*)&Bs[p * 64 + rr][sg] = pb[p];
    __syncthreads();
    if (it + 1 < nIt) {
      long k = kbeg + (long)(it + 1) * 32;
      long kb = bmod ? (k & (bmod - 1)) : k;
#pragma unroll
      for (int p = 0; p < 2; ++p) {
        int row = p * 64 + rr;
        uint4 va = {0,0,0,0};
        if (m0 + row < M) va = *(const uint4*)(A + (m0 + row) * lda + k + sg);
        pa[p] = va;
      }
#pragma unroll
      for (int p = 0; p < NP; ++p) {
        int row = p * 64 + rr;
        uint4 vb = {0,0,0,0};
        if (n0 + row < N) vb = *(const uint4*)(B + (n0 + row) * ldb + kb + sg);
        pb[p] = vb;
      }
    }
    f16x8 af[4], bf[NJ];
#pragma unroll
    for (int i = 0; i < 4; ++i) af[i] = *(const f16x8*)&As[wm + i*16 + lc][lr * 8];
#pragma unroll
    for (int j = 0; j < NJ; ++j) bf[j] = *(const f16x8*)&Bs[wn + j*16 + lc][lr * 8];
#pragma unroll
    for (int i = 0; i < 4; ++i)
#pragma unroll
      for (int j = 0; j < NJ; ++j)
        acc[i][j] = __builtin_amdgcn_mfma_f32_16x16x32_f16(af[i], bf[j], acc[i][j], 0, 0, 0);
    __syncthreads();
  }

  if (outF)  outF  += (long)batch * sF + (long)slice * sSl;
  if (outH)  outH  += (long)batch * sH;
  if (outH2) outH2 += (long)batch * sH2;
  if (out2)  out2  += (long)batch * s2;
#pragma unroll
  for (int i = 0; i < 4; ++i)
#pragma unroll
    for (int j = 0; j < NJ; ++j)
#pragma unroll
      for (int r = 0; r < 4; ++r) {
        long row = m0 + wm + i * 16 + lr * 4 + r;
        long col = n0 + wn + j * 16 + lc;
        if (row < M && col < N) {
          float v = acc[i][j][r];
          if (row >= brow0) {
            if (bias1) v += bias1[col];
            if (bias2) v += bias2[col];
          }
          if (act)   v = tanhf(v);
          if (outF) {
            long fc = ilv ? ((col & 1023) * 4 + (col >> 10)) : col;
            outF[row * ldF + fc] = v;
          }
          if (outH)  outH[row * ldH + col] = (f16)v;
          if (outH2) outH2[row * ldH2 + col] = (f16)v;
          if (out2) {
            f16 hi = (f16)v;
            out2[row * ld2 + col]        = hi;
            out2[row * ld2 + 1024 + col] = (f16)(v - (float)hi);
          }
        }
      }
}

// ---------------------------------------------------------------------------
// Persistent LSTM + hidden NL transpose. 256 blocks x 256 threads, 1 blk/CU:
//   blocks 0..127:  R3-structure LSTM with ACK-FREE publish: producer fires
//     data (sc0 sc1) then immediately fires the wave flag -- the vmcnt(0)
//     ack round-trip is removed from the critical path. The flag is a HINT;
//     truth is the data itself: st slots 1..128 are pre-poisoned (0xFFFF =
//     f16 -NaN, unproducible by h=o*tanh(c)), and consumers poison-verify
//     the A-burst, retrying only on a rare in-flight race.
//   blocks 128..255: transpose nl -> ctxT/ctx_h (hidden, R8/R9-verified).
__global__ __launch_bounds__(256) void k_lstm_all(
    const f16* __restrict__ Whh,          // (4096,1024)
    const float* __restrict__ nt_table,   // (232,1024,4) gate-interleaved
    const float* __restrict__ prod_gates, // rows 200+ of nt_table
    const int* __restrict__ nt_ids,       // (128,32)
    const float* __restrict__ c0,         // (32,1024)
    f16* __restrict__ st,                 // (129,128,32,8); slots 1.. poisoned
    f16* __restrict__ q2,                 // (4096,2048) hi|lo
    f16* __restrict__ X,                  // (4096,3072)
    f16* __restrict__ Y1,                 // (4096,2048)
    int* __restrict__ flags,              // 512 dense ints: [bx][wave]
    const float* __restrict__ nl,         // (32,512,1024) fp32
    f16* __restrict__ ctxT, f16* __restrict__ ctxN)
{
  __shared__ __align__(16) f16 whh_s[32][1032];
  __shared__ float partial[2][4][32][34];
  __shared__ float tile[32][33];
  const int tid = threadIdx.x;
  const int bx = blockIdx.x;

  if (bx >= 128) {
    // ---------------- nl transpose worker ----------------
    const int me = bx - 128;
    const int c = tid & 31, r = tid >> 5;
    for (int idx = me; idx < 16384; idx += 128) {
      int b = idx >> 9, rr2 = idx & 511;
      int l0 = (rr2 & 15) * 32, h0v = (rr2 >> 4) * 32;
      const float* inb = nl + (long)b * 512 * 1024;
      f16* oTb = ctxT + (long)b * 1024 * 512;
      f16* oNb = ctxN + (long)b * 512 * 1024;
#pragma unroll
      for (int p = 0; p < 4; ++p) {
        float v = inb[(long)(l0 + r + p*8) * 1024 + h0v + c];
        tile[r + p*8][c] = v;
        oNb[(long)(l0 + r + p*8) * 1024 + h0v + c] = (f16)v;
      }
      __syncthreads();
#pragma unroll
      for (int p = 0; p < 4; ++p)
        oTb[(long)(h0v + r + p*8) * 512 + l0 + c] = (f16)tile[c][r + p*8];
      __syncthreads();   // tile reused next iteration
    }
    return;
  }

  // ---------------- LSTM ----------------
  const int w = tid >> 6, lane = tid & 63;
  const int lr = lane >> 4, lc = lane & 15;
  const int j0 = bx * 8;

  // stage Whh slice: LDS row r=(g*8+jj) <- global row g*1024 + j0 + jj
  for (int i = tid; i < 32 * 128; i += 256) {
    int r = i >> 7, c8 = i & 127;
    int g = r >> 3, jj = r & 7;
    *(uint4*)&whh_s[r][c8 * 8] =
        *(const uint4*)(Whh + ((long)g * 1024 + j0 + jj) * 1024 + c8 * 8);
  }
  const int b_own = tid >> 3, jj_own = tid & 7;
  const int j_own = j0 + jj_own;
  float c_reg = c0[(long)b_own * 1024 + j_own];
  float4 pg4 = *(const float4*)(prod_gates + (long)b_own * 4096 + j_own * 4);
  int nid0 = nt_ids[b_own];
  float4 nt4 = *(const float4*)(nt_table + (long)nid0 * 4096 + j_own * 4);
  __syncthreads();   // whh_s ready

  // hoist step-invariant B fragments LDS -> registers (whh_s dead afterwards)
  f16x8 B0[8], B1[8];
#pragma unroll
  for (int kt = 0; kt < 8; ++kt) {
    int k = w * 256 + kt * 32 + lr * 8;
    B0[kt] = *(const f16x8*)&whh_s[lc][k];
    B1[kt] = *(const f16x8*)&whh_s[16 + lc][k];
  }

  // A base: fragment kt of wave w = st[t][w*32+kt*4+lr][lc or 16+lc][0..8)
  const f16* pA = st + (long)(w * 32 + lr) * 256 + lc * 8;
  const int* fp = flags + w * 128 + lane * 2;   // this wave's 128 producer flags

  for (int t = 0; t < TT; ++t) {
    // ---- poll producer flags (hint: makes first-try success likely) ----
    if (t > 0) {
      int done = 0;
      while (true) {
        if (!done) {
          i32x2 ff;
          asm volatile("global_load_dwordx2 %0, %1, off sc0 sc1\n\t"
                       "s_waitcnt vmcnt(0)"
                       : "=&v"(ff) : "v"(fp) : "memory");
          done = (ff.x >= t) & (ff.y >= t);
        }
        if (__all(done)) break;
        __builtin_amdgcn_s_sleep(1);
      }
    }

    // ---- A-burst with poison verify (truth); retry only on rare race ----
    u32x4 A0[8], A1[8];
    {
      const f16* pt = pA + (long)t * 32768;
      while (true) {
#pragma unroll
        for (int q = 0; q < 4; ++q) {
          asm volatile(
            "global_load_dwordx4 %0, %4, off sc0 sc1\n\t"
            "global_load_dwordx4 %1, %4, off offset:256 sc0 sc1\n\t"
            "global_load_dwordx4 %2, %4, off offset:2048 sc0 sc1\n\t"
            "global_load_dwordx4 %3, %4, off offset:2304 sc0 sc1"
            : "=&v"(A0[2*q]), "=&v"(A1[2*q]), "=&v"(A0[2*q+1]), "=&v"(A1[2*q+1])
            : "v"(pt + (long)q * 2048) : "memory");
        }
        asm volatile("s_waitcnt vmcnt(0)" ::: "memory");
        unsigned mA = 0, mB = 0, mC = 0, mD = 0;
#pragma unroll
        for (int kt = 0; kt < 8; ++kt) {
          asm("v_pk_max_u16 %0, %0, %1" : "+v"(mA) : "v"(A0[kt].x));
          asm("v_pk_max_u16 %0, %0, %1" : "+v"(mB) : "v"(A0[kt].y));
          asm("v_pk_max_u16 %0, %0, %1" : "+v"(mC) : "v"(A0[kt].z));
          asm("v_pk_max_u16 %0, %0, %1" : "+v"(mD) : "v"(A0[kt].w));
          asm("v_pk_max_u16 %0, %0, %1" : "+v"(mA) : "v"(A1[kt].x));
          asm("v_pk_max_u16 %0, %0, %1" : "+v"(mB) : "v"(A1[kt].y));
          asm("v_pk_max_u16 %0, %0, %1" : "+v"(mC) : "v"(A1[kt].z));
          asm("v_pk_max_u16 %0, %0, %1" : "+v"(mD) : "v"(A1[kt].w));
        }
        asm("v_pk_max_u16 %0, %0, %1" : "+v"(mA) : "v"(mB));
        asm("v_pk_max_u16 %0, %0, %1" : "+v"(mC) : "v"(mD));
        asm("v_pk_max_u16 %0, %0, %1" : "+v"(mA) : "v"(mC));
        int ok = !(((mA & 0xFFFFu) == 0xFFFFu) || ((mA >> 16) == 0xFFFFu));
        if (__all(ok)) break;
        __builtin_amdgcn_s_sleep(1);
      }
      __builtin_amdgcn_sched_barrier(0);   // no MFMA hoist above the waitcnt
    }

    // prefetch next step's nt gates (off the critical path)
    float4 nt4n = nt4;
    if (t + 1 < TT) {
      int nidn = nt_ids[(t + 1) * 32 + b_own];
      nt4n = *(const float4*)(nt_table + (long)nidn * 4096 + j_own * 4);
    }

    f32x4 acc[2][2];
#pragma unroll
    for (int i = 0; i < 2; ++i)
#pragma unroll
      for (int j = 0; j < 2; ++j) { f32x4 zz = {0.f,0.f,0.f,0.f}; acc[i][j] = zz; }
#pragma unroll
    for (int kt = 0; kt < 8; ++kt) {
      f16x8 a0v = __builtin_bit_cast(f16x8, A0[kt]);
      f16x8 a1v = __builtin_bit_cast(f16x8, A1[kt]);
      acc[0][0] = __builtin_amdgcn_mfma_f32_16x16x32_f16(a0v, B0[kt], acc[0][0], 0, 0, 0);
      acc[0][1] = __builtin_amdgcn_mfma_f32_16x16x32_f16(a0v, B1[kt], acc[0][1], 0, 0, 0);
      acc[1][0] = __builtin_amdgcn_mfma_f32_16x16x32_f16(a1v, B0[kt], acc[1][0], 0, 0, 0);
      acc[1][1] = __builtin_amdgcn_mfma_f32_16x16x32_f16(a1v, B1[kt], acc[1][1], 0, 0, 0);
    }
    float (*pp)[32][34] = partial[t & 1];
#pragma unroll
    for (int mi = 0; mi < 2; ++mi)
#pragma unroll
      for (int ni = 0; ni < 2; ++ni)
#pragma unroll
        for (int r = 0; r < 4; ++r)
          pp[w][ni * 16 + lc][mi * 16 + lr * 4 + r] = acc[mi][ni][r];
    __syncthreads();

    // reduce 4 K-slices + LSTM cell (double-buffered partial: no 2nd barrier)
    float g4[4];
#pragma unroll
    for (int g = 0; g < 4; ++g) {
      int rrow = g * 8 + jj_own;
      g4[g] = pp[0][rrow][b_own] + pp[1][rrow][b_own] +
              pp[2][rrow][b_own] + pp[3][rrow][b_own];
    }
    float ii = sigmoidf_(g4[0] + nt4.x + pg4.x);
    float ff = sigmoidf_(g4[1] + nt4.y + pg4.y);
    float gg = tanhf(g4[2] + nt4.z + pg4.z);
    float oo = sigmoidf_(g4[3] + nt4.w + pg4.w);
    c_reg = ff * c_reg + ii * gg;
    float hn = oo * tanhf(c_reg);
    f16 hi = (f16)hn;

    // ---- publish h_{t+1}: data fire -> flag fire (NO vmcnt ack) ----
    if (t + 1 < TT) {
      union { f16 h; unsigned short u; } cv; cv.h = hi;
      unsigned me2 = cv.u;
      unsigned d  = me2 | ((unsigned)__shfl_down((int)me2, 1) << 16);
      unsigned d2 = (unsigned)__shfl_down((int)d, 2);
      unsigned e0 = (unsigned)__shfl_down((int)d, 4);
      unsigned e1 = (unsigned)__shfl_down((int)d2, 4);
      if (jj_own == 0) {
        u32x4 pay; pay.x = d; pay.y = d2; pay.z = e0; pay.w = e1;
        f16* pst = st + (long)(t + 1) * 32768 + bx * 256 + b_own * 8;
        asm volatile("global_store_dwordx4 %0, %1, off sc0 sc1"
                     :: "v"(pst), "v"(pay) : "memory");
      }
      if (lane == 0) {
        int* myf = flags + bx * 4 + w;
        int fv = t + 1;
        asm volatile("global_store_dword %0, %1, off sc0 sc1"
                     :: "v"(myf), "v"(fv) : "memory");
      }
    }

    // non-critical stores: complete in the shadow of the next poll
    long row = (long)b_own * 128 + t;
    q2[row * 2048 + j_own]        = hi;
    q2[row * 2048 + 1024 + j_own] = (f16)(hn - (float)hi);
    X[row * 3072 + j_own]         = hi;
    Y1[row * 2048 + 1024 + j_own] = hi;

    nt4 = nt4n;
  }
}

// ---------------------------------------------------------------------------
// Row softmax over 512 cols of sum of 4 fp32 planes -> fp16. One block/row.
__global__ __launch_bounds__(256) void k_softmax4(const float* __restrict__ p,
                                                  long pstride,
                                                  f16* __restrict__ out) {
  long row = blockIdx.x;
  const float* p0 = p + row * 512;
  out += row * 512;
  const int tid = threadIdx.x, w = tid >> 6, lane = tid & 63;
  float vx = 0.f, vy = 0.f;
#pragma unroll
  for (int s = 0; s < 4; ++s) {
    float2 a = ((const float2*)(p0 + s * pstride))[tid];
    vx += a.x; vy += a.y;
  }
  float m = fmaxf(vx, vy);
#pragma unroll
  for (int off = 32; off; off >>= 1) m = fmaxf(m, __shfl_xor(m, off));
  __shared__ float red[8];
  if (lane == 0) red[w] = m;
  __syncthreads();
  m = fmaxf(fmaxf(red[0], red[1]), fmaxf(red[2], red[3]));
  float e0 = __expf(vx - m), e1 = __expf(vy - m);
  float s2 = e0 + e1;
#pragma unroll
  for (int off = 32; off; off >>= 1) s2 += __shfl_xor(s2, off);
  if (lane == 0) red[4 + w] = s2;
  __syncthreads();
  s2 = red[4] + red[5] + red[6] + red[7];
  float inv = 1.0f / s2;
  out[tid * 2]     = (f16)(e0 * inv);
  out[tid * 2 + 1] = (f16)(e1 * inv);
}

// ---------------------------------------------------------------------------
extern "C" void kernel_launch(void* const* d_in, const int* in_sizes, int n_in,
                              void* d_out, int out_size, void* d_ws, size_t ws_size,
                              hipStream_t stream)
{
  const int*   init_prod = (const int*)d_in[0];
  const int*   nt_ids    = (const int*)d_in[1];
  const float* h0   = (const float*)d_in[2];
  const float* c0   = (const float*)d_in[3];
  const float* nl   = (const float*)d_in[4];
  const float* env  = (const float*)d_in[5];
  const float* nt_emb   = (const float*)d_in[6];
  const float* rule_emb = (const float*)d_in[7];
  const float* W_ih = (const float*)d_in[8];
  const float* W_hh = (const float*)d_in[9];
  const float* b_ih = (const float*)d_in[10];
  const float* b_hh = (const float*)d_in[11];
  const float* Wz   = (const float*)d_in[12];
  const float* bz   = (const float*)d_in[13];
  const float* We   = (const float*)d_in[14];
  const float* be   = (const float*)d_in[15];
  const float* Wc   = (const float*)d_in[16];
  const float* bc   = (const float*)d_in[17];
  float* out = (float*)d_out;
  (void)in_sizes; (void)n_in; (void)out_size; (void)ws_size;

  size_t off = 0;
  auto carve = [&](size_t bytes) {
    char* p = (char*)d_ws + off;
    off += (bytes + 255) & ~(size_t)255;
    return (void*)p;
  };
  // Total carve ~209 MB -- the R3/R5/R8/R9/R11 proven-safe envelope.
  f16*   Whh_h   = (f16*)carve(4096L * 1024 * 2);
  f16*   Wz_h    = (f16*)carve(1024L * 2048 * 2);
  f16*   We_h    = (f16*)carve(1024L * 2048 * 2);
  f16*   Wc_h    = (f16*)carve(1024L * 3072 * 2);
  f16*   xcat    = (f16*)carve(232L * 2048 * 2);        // merged gate A operand
  float* nt_table = (float*)carve(232L * 4096 * 4);     // rows 200+ = prod_gates
  f16*   st_hi   = (f16*)carve(129L * 128 * 32 * 8 * 2);  // [t][bx][b][jj]
  f16*   q2      = (f16*)carve(4096L * 2048 * 2);   // query hi|lo (h, then zt)
  f16*   X       = (f16*)carve(4096L * 3072 * 2);   // [h | zt | et] for ct GEMM
  f16*   Y1      = (f16*)carve(4096L * 2048 * 2);   // [mix1 | h]  for zt GEMM
  f16*   Y2      = (f16*)carve(4096L * 2048 * 2);   // [mix2 | zt] for et GEMM
  f16*   ctx_h   = (f16*)carve(32L * 512 * 1024 * 2);   // shared nl->env
  f16*   ctxT    = (f16*)carve(32L * 1024 * 512 * 2);   // shared nl->env
  float* scoresP = (float*)carve(4L * 32 * 128 * 512 * 4);  // 4 split-K planes
  f16*   attn    = (f16*)carve(4096L * 512 * 2);
  int*   bar     = (int*)carve(2048);   // 512 dense flags
  f16*   Wih_h   = (f16*)X;   // alias: Wih dead before LSTM writes X

  // fused prep: converts + xcat + h0 seed + st poison + flag zero (one launch)
  k_prep<<<dim3(8192), dim3(256), 0, stream>>>(
      W_ih, W_hh, Wz, We, Wc, nt_emb, rule_emb, init_prod, h0,
      Wih_h, Whh_h, Wz_h, We_h, Wc_h, xcat, st_hi, bar);

  auto gemm = [&](const f16* A, long lda, long sA,
                  const f16* B, long ldb, long sB,
                  float* oF, long ldF, long sF, long sSl,
                  f16* oH, long ldH, long sH,
                  f16* oH2, long ldH2, long sH2,
                  f16* o2, long ld2, long s2,
                  const float* b1, const float* b2,
                  int M, int N, int K, int act, int bmod, int zdiv, int ilv,
                  int batch, const float* tin, f16* tT, f16* tN, int brow0,
                  int ncols) {
    dim3 grid((unsigned)((M + 127) / 128), (unsigned)((N + ncols - 1) / ncols),
              (unsigned)(batch * zdiv + (tin ? 1 : 0)));
    if (ncols == 64)
      k_gemm<64><<<grid, dim3(256), 0, stream>>>(A, lda, sA, B, ldb, sB,
                                                 oF, ldF, sF, sSl, oH, ldH, sH,
                                                 oH2, ldH2, sH2, o2, ld2, s2,
                                                 b1, b2, M, N, K, act, bmod,
                                                 zdiv, ilv, tin, tT, tN, brow0);
    else
      k_gemm<128><<<grid, dim3(256), 0, stream>>>(A, lda, sA, B, ldb, sB,
                                                  oF, ldF, sF, sSl, oH, ldH, sH,
                                                  oH2, ldH2, sH2, o2, ld2, s2,
                                                  b1, b2, M, N, K, act, bmod,
                                                  zdiv, ilv, tin, tT, tN, brow0);
  };
  const long SPL = 32L * 128 * 512;   // split-K plane stride (floats)

  // merged gate tables: [nte|0 ; 0|prod] @ W_ih^T, biases on rows >= 200
  gemm(xcat, 2048, 0, Wih_h, 2048, 0, nt_table, 4096, 0, 0,
       nullptr,0,0, nullptr,0,0, nullptr,0,0, b_ih, b_hh,
       232, 4096, 2048, 0, 0, 1, 1, 1, nullptr, nullptr, nullptr, 200, 128);

  // persistent LSTM (blocks 0-127) + hidden nl transpose (blocks 128-255)
  k_lstm_all<<<dim3(256), dim3(256), 0, stream>>>(
      Whh_h, nt_table, nt_table + 200L * 4096, nt_ids, c0, st_hi, q2, X, Y1,
      bar, nl, ctxT, ctx_h);

  // --- attention over nl (ctx buffers filled by the fused LSTM kernel) ---
  gemm(q2, 2048, 128L * 2048, ctx_h, 1024, 512L * 1024,
       scoresP, 512, 128L * 512, SPL, nullptr,0,0, nullptr,0,0, nullptr,0,0,
       nullptr, nullptr, 128, 512, 2048, 0, 1024, 4, 0, 32,
       nullptr, nullptr, nullptr, 0, 128);
  k_softmax4<<<dim3(4096), dim3(256), 0, stream>>>(scoresP, SPL, attn);
  gemm(attn, 512, 128L * 512, ctxT, 512, 1024L * 512,
       nullptr,0,0,0, Y1, 2048, 128L * 2048, nullptr,0,0, nullptr,0,0,
       nullptr, nullptr, 128, 1024, 512, 0, 0, 1, 0, 32,
       nullptr, nullptr, nullptr, 0, 64);
  // zt = tanh(Y1 @ Wz^T + bz) -> X[:,1024:2048), Y2[:,1024:2048), q2
  //   + side-crew layer transposes env -> ctxT/ctx_h (both nl ctx dead here)
  gemm(Y1, 2048, 0, Wz_h, 2048, 0,
       nullptr,0,0,0, X + 1024, 3072, 0, Y2 + 1024, 2048, 0, q2, 2048, 0,
       bz, nullptr, 4096, 1024, 2048, 1, 0, 1, 0, 1,
       env, ctxT, ctx_h, 0, 64);

  // --- attention over env (ctx buffers rewritten inside the zt launch) ---
  gemm(q2, 2048, 128L * 2048, ctx_h, 1024, 512L * 1024,
       scoresP, 512, 128L * 512, SPL, nullptr,0,0, nullptr,0,0, nullptr,0,0,
       nullptr, nullptr, 128, 512, 2048, 0, 1024, 4, 0, 32,
       nullptr, nullptr, nullptr, 0, 128);
  k_softmax4<<<dim3(4096), dim3(256), 0, stream>>>(scoresP, SPL, attn);
  gemm(attn, 512, 128L * 512, ctxT, 512, 1024L * 512,
       nullptr,0,0,0, Y2, 2048, 128L * 2048, nullptr,0,0, nullptr,0,0,
       nullptr, nullptr, 128, 1024, 512, 0, 0, 1, 0, 32,
       nullptr, nullptr, nullptr, 0, 64);
  // et = tanh(Y2 @ We^T + be) -> X[:,2048:3072)
  gemm(Y2, 2048, 0, We_h, 2048, 0,
       nullptr,0,0,0, X + 2048, 3072, 0, nullptr,0,0, nullptr,0,0,
       be, nullptr, 4096, 1024, 2048, 1, 0, 1, 0, 1,
       nullptr, nullptr, nullptr, 0, 64);

  // --- ct = tanh(X=[h|zt|et] @ Wc^T + bc) -> d_out (T,B,H) ---
  gemm(X, 3072, 128L * 3072, Wc_h, 3072, 0,
       out, 32L * 1024, 1024, 0, nullptr,0,0, nullptr,0,0, nullptr,0,0,
       bc, nullptr, 128, 1024, 3072, 1, 0, 1, 0, 32,
       nullptr, nullptr, nullptr, 0, 64);
}